// Round 9
// baseline (271.788 us; speedup 1.0000x reference)
//
#include <hip/hip_runtime.h>
#include <hip/hip_bf16.h>

#define B_ 2
#define S_ 2048
#define D_ 1024
#define H_ 16
#define DK_ 64
#define M_ (B_*S_)          // 4096 token rows

typedef __bf16 bf16;
typedef __bf16 bf16x8 __attribute__((ext_vector_type(8)));
typedef __bf16 bf16x4 __attribute__((ext_vector_type(4)));
typedef __bf16 bf16x2 __attribute__((ext_vector_type(2)));
typedef float  f32x4  __attribute__((ext_vector_type(4)));
typedef float  f32x16 __attribute__((ext_vector_type(16)));
typedef int    i32x4  __attribute__((ext_vector_type(4)));

#define GLOAD_LDS16(gp, lp) __builtin_amdgcn_global_load_lds( \
    (const __attribute__((address_space(1))) void*)(gp),      \
    (__attribute__((address_space(3))) void*)(lp), 16, 0, 0)

// pack two f32 -> one u32 of 2 bf16 (pure C++, no asm)
static __device__ __forceinline__ int packbf(float a, float b) {
  bf16x2 t; t[0] = (bf16)a; t[1] = (bf16)b;
  return __builtin_bit_cast(int, t);
}

// ---------------- fp32 -> bf16 cast (vectorized x8) ----------------
__global__ __launch_bounds__(256) void cast_kernel(
    const float* __restrict__ q, const float* __restrict__ k, const float* __restrict__ v,
    const float* __restrict__ wq, const float* __restrict__ wk,
    const float* __restrict__ wv, const float* __restrict__ wo,
    bf16* __restrict__ dst)
{
  const size_t XN = (size_t)M_ * D_;   // 4Mi
  const size_t WN = (size_t)D_ * D_;   // 1Mi
  size_t e = ((size_t)blockIdx.x * 256 + threadIdx.x) * 8;
  const float* src; size_t off;
  if (e < XN)        { src = q; off = e; }
  else if (e < 2*XN) { src = k; off = e - XN; }
  else if (e < 3*XN) { src = v; off = e - 2*XN; }
  else {
    size_t w = e - 3*XN; size_t wi = w >> 20; off = w & (WN - 1);
    src = (wi == 0) ? wq : (wi == 1) ? wk : (wi == 2) ? wv : wo;
  }
  float4 a = *reinterpret_cast<const float4*>(src + off);
  float4 b = *reinterpret_cast<const float4*>(src + off + 4);
  bf16x8 o;
  o[0]=(bf16)a.x; o[1]=(bf16)a.y; o[2]=(bf16)a.z; o[3]=(bf16)a.w;
  o[4]=(bf16)b.x; o[5]=(bf16)b.y; o[6]=(bf16)b.z; o[7]=(bf16)b.w;
  *reinterpret_cast<bf16x8*>(dst + e) = o;
}

// ---------------- shared NT-GEMM mainloop: C = A(MxK) * W(NxK)^T (128x128) ----------------
__device__ __forceinline__ void gemm_mainloop_128(
    const bf16* __restrict__ A, const bf16* __restrict__ W,
    int m0, int n0, int Kdim, bf16* As, bf16* Bs, f32x4 acc[4][4])
{
  const int tid  = threadIdx.x;
  const int lane = tid & 63;
  const int wave = tid >> 6;
  const int wr   = wave >> 1;
  const int wc   = wave & 1;
  const int g    = lane >> 4;
  const int c    = lane & 15;

#pragma unroll
  for (int i = 0; i < 4; ++i)
#pragma unroll
    for (int j = 0; j < 4; ++j)
      acc[i][j] = (f32x4){0.f, 0.f, 0.f, 0.f};

  for (int kt = 0; kt < Kdim; kt += 32) {
    __syncthreads();
#pragma unroll
    for (int u = 0; u < 2; ++u) {
      int ch  = tid + u*256;          // 16B chunk id, 512 per tile
      int row = ch >> 2;              // 4 chunks per 64B row
      int col = (ch & 3) * 8;         // elements
      GLOAD_LDS16(A + (size_t)(m0 + row)*Kdim + kt + col, As + ch*8);
      GLOAD_LDS16(W + (size_t)(n0 + row)*Kdim + kt + col, Bs + ch*8);
    }
    __syncthreads();

    bf16x8 af[4], bw[4];
#pragma unroll
    for (int i = 0; i < 4; ++i)
      af[i] = *reinterpret_cast<const bf16x8*>(As + (wr*64 + i*16 + c)*32 + g*8);
#pragma unroll
    for (int j = 0; j < 4; ++j)
      bw[j] = *reinterpret_cast<const bf16x8*>(Bs + (wc*64 + j*16 + c)*32 + g*8);
#pragma unroll
    for (int i = 0; i < 4; ++i)
#pragma unroll
      for (int j = 0; j < 4; ++j)
        acc[i][j] = __builtin_amdgcn_mfma_f32_16x16x32_bf16(af[i], bw[j], acc[i][j], 0, 0, 0);
  }
}

// ---------------- QKV projection; Q,K -> [B,H,S,DK] (Q pre-scaled), V -> [B,H,DK,S] ----------------
__global__ __launch_bounds__(256) void gemm_qkv_kernel(
    const bf16* __restrict__ X, const bf16* __restrict__ Wb,
    const float* __restrict__ bq, const float* __restrict__ bk, const float* __restrict__ bv,
    bf16* __restrict__ Qo, bf16* __restrict__ Ko, bf16* __restrict__ Vo)
{
  __shared__ bf16 As[128*32];
  __shared__ bf16 Bs[128*32];
  const int z  = blockIdx.z;
  const int m0 = blockIdx.y * 128;
  const int n0 = blockIdx.x * 128;
  const bf16* A = X  + (size_t)z * ((size_t)M_ * D_);
  const bf16* W = Wb + (size_t)z * ((size_t)D_ * D_);
  const float* bias = (z == 0) ? bq : (z == 1) ? bk : bv;
  // fold (1/sqrt(DK))*log2(e) into Q so attention softmax runs in exp2 domain
  const float sc = (z == 0) ? 0.18033688011112042f : 1.0f;

  f32x4 acc[4][4];
  gemm_mainloop_128(A, W, m0, n0, D_, As, Bs, acc);

  const int lane = threadIdx.x & 63;
  const int wave = threadIdx.x >> 6;
  const int wr = wave >> 1, wc = wave & 1;
  const int g = lane >> 4,  c = lane & 15;
  bf16* dstQK = (z == 0) ? Qo : Ko;

#pragma unroll
  for (int i = 0; i < 4; ++i) {
#pragma unroll
    for (int j = 0; j < 4; ++j) {
      const int n  = n0 + wc*64 + j*16 + c;
      const float bn = bias[n];
      const int h = n >> 6, dk = n & 63;
      const int mrow = m0 + wr*64 + i*16 + g*4;     // 4 consecutive m
      if (z == 2) {
        const int b = mrow >> 11, s = mrow & 2047;  // 4 consecutive s, no b crossing
        bf16x4 pv;
#pragma unroll
        for (int r = 0; r < 4; ++r) pv[r] = (bf16)(acc[i][j][r] + bn);
        *reinterpret_cast<bf16x4*>(Vo + ((size_t)((b*H_ + h)*DK_ + dk))*S_ + s) = pv;
      } else {
#pragma unroll
        for (int r = 0; r < 4; ++r) {
          const int m = mrow + r;
          const int b = m >> 11, s = m & 2047;
          dstQK[((size_t)((b*H_ + h)*S_ + s))*DK_ + dk] = (bf16)((acc[i][j][r] + bn) * sc);
        }
      }
    }
  }
}

// ---------------- output projection: 64x128 tile (512 blocks -> 2/CU), fp32 out + bias ----------------
__global__ __launch_bounds__(256) void gemm_out_kernel(
    const bf16* __restrict__ A, const bf16* __restrict__ W,
    const float* __restrict__ bias, float* __restrict__ out)
{
  __shared__ bf16 As[64*32];
  __shared__ bf16 Bs[128*32];
  const int m0 = blockIdx.y * 64;
  const int n0 = blockIdx.x * 128;
  const int tid  = threadIdx.x;
  const int lane = tid & 63;
  const int wave = tid >> 6;
  const int wr = wave >> 1, wc = wave & 1;   // 2x2 waves over (64m, 128n)
  const int g = lane >> 4,  c = lane & 15;

  f32x4 acc[2][4];
#pragma unroll
  for (int i = 0; i < 2; ++i)
#pragma unroll
    for (int j = 0; j < 4; ++j)
      acc[i][j] = (f32x4){0.f, 0.f, 0.f, 0.f};

  for (int kt = 0; kt < D_; kt += 32) {
    __syncthreads();
    {
      int ch  = tid;                  // A: 256 chunks (64 rows x 4)
      int row = ch >> 2;
      int col = (ch & 3) * 8;
      GLOAD_LDS16(A + (size_t)(m0 + row)*D_ + kt + col, As + ch*8);
#pragma unroll
      for (int u = 0; u < 2; ++u) {   // B: 512 chunks (128 rows x 4)
        int chb  = tid + u*256;
        int rowb = chb >> 2;
        int colb = (chb & 3) * 8;
        GLOAD_LDS16(W + (size_t)(n0 + rowb)*D_ + kt + colb, Bs + chb*8);
      }
    }
    __syncthreads();

    bf16x8 af[2], bw[4];
#pragma unroll
    for (int i = 0; i < 2; ++i)
      af[i] = *reinterpret_cast<const bf16x8*>(As + (wr*32 + i*16 + c)*32 + g*8);
#pragma unroll
    for (int j = 0; j < 4; ++j)
      bw[j] = *reinterpret_cast<const bf16x8*>(Bs + (wc*64 + j*16 + c)*32 + g*8);
#pragma unroll
    for (int i = 0; i < 2; ++i)
#pragma unroll
      for (int j = 0; j < 4; ++j)
        acc[i][j] = __builtin_amdgcn_mfma_f32_16x16x32_bf16(af[i], bw[j], acc[i][j], 0, 0, 0);
  }

#pragma unroll
  for (int i = 0; i < 2; ++i) {
#pragma unroll
    for (int j = 0; j < 4; ++j) {
      const int n = n0 + wc*64 + j*16 + c;
      const float bn = bias[n];
      const int mrow = m0 + wr*32 + i*16 + g*4;
#pragma unroll
      for (int r = 0; r < 4; ++r)
        out[(size_t)(mrow + r)*D_ + n] = acc[i][j][r] + bn;
    }
  }
}

// ---------------- causal flash attention v2 ----------------
// 2 waves x 64 q-rows (2 frags of 32) = 128 q/block, 128 threads.
// 512 blocks -> 4 blocks/CU (2 waves/SIMD). KV tiles of 64, double-buffered LDS.
// K/V LDS reads SHARED across both q-frags (2x MFMA per ds_read).
// Balanced 1D grid: each CU gets one big + one small causal block.
// Zero inline asm; cross-half exchange via __shfl_xor (R8-proven).
__global__ __launch_bounds__(128, 2) void attn_kernel(
    const bf16* __restrict__ Q, const bf16* __restrict__ K,
    const bf16* __restrict__ Vt, bf16* __restrict__ O)
{
  const int bx   = blockIdx.x;
  const int qt   = (bx < 256) ? (15 - (bx >> 5)) : ((bx - 256) >> 5);  // big+small pairing
  const int bh   = bx & 31;
  const int b    = bh >> 4;
  const int hh   = bh & 15;
  const int q0   = qt * 128;
  const int tid  = threadIdx.x;
  const int wave = tid >> 6;      // 0/1
  const int lane = tid & 63;
  const int ql   = lane & 31;
  const int hi   = lane >> 5;

  const float NEG = -30000.0f;    // masked-score sentinel; exp2f(<= -30000) == 0 exactly

  __shared__ bf16 Kl[2][64*64];   // [kv][d] rows of 128B, slot-swizzled
  __shared__ bf16 Vl[2][64*64];   // [dk][kv] rows of 128B, slot-swizzled

  const bf16* Qh = Q  + (size_t)bh * (S_*DK_);
  const bf16* Kh = K  + (size_t)bh * (S_*DK_);
  const bf16* Vh = Vt + (size_t)bh * (DK_*S_);

  const int qw0 = q0 + wave*64;   // wave owns q rows [qw0, qw0+64)

  // Q as B-operand of S^T = K*Q^T: frag f covers q rows qw0+f*32..+31
  bf16x8 qf[2][4];
#pragma unroll
  for (int f = 0; f < 2; ++f)
#pragma unroll
    for (int ck = 0; ck < 4; ++ck)
      qf[f][ck] = *reinterpret_cast<const bf16x8*>(
          Qh + (size_t)(qw0 + f*32 + ql)*DK_ + ck*16 + hi*8);

  f32x16 o_[2][2];                // [frag][dk-half]; O^T col=q=ql, row dk=(r&3)+8*(r>>2)+4*hi
#pragma unroll
  for (int f = 0; f < 2; ++f) { o_[f][0] = (f32x16){}; o_[f][1] = (f32x16){}; }
  float m_[2] = {0.f, 0.f}, l_[2] = {0.f, 0.f};

  const int nt = q0/64 + 2;       // kv tiles covering [0, q0+128)

#define STAGE_KV(kv0s, bb) do {                                              \
  _Pragma("unroll")                                                          \
  for (int u = 0; u < 4; ++u) {                                              \
    int ch  = tid + u*128;            /* 512 chunks of 16B per 8KB tile */   \
    int row = ch >> 3;                                                       \
    int g   = (ch & 7) ^ (row & 7);   /* pre-swizzled source slot */         \
    GLOAD_LDS16(Kh + (size_t)((kv0s) + row)*DK_ + g*8, &Kl[bb][ch*8]);       \
    GLOAD_LDS16(Vh + (size_t)row*S_ + (kv0s) + g*8,    &Vl[bb][ch*8]);       \
  }                                                                          \
} while (0)

// build one PV B-operand fragment from 8 P values (pure shfl + select)
#define MK_PA(dst, s, base) do {                                               \
    int x0 = packbf(s[(base)+0], s[(base)+1]);                                 \
    int x1 = packbf(s[(base)+2], s[(base)+3]);                                 \
    int y0 = packbf(s[(base)+4], s[(base)+5]);                                 \
    int y1 = packbf(s[(base)+6], s[(base)+7]);                                 \
    int px0 = __shfl_xor(x0, 32), px1 = __shfl_xor(x1, 32);                    \
    int py0 = __shfl_xor(y0, 32), py1 = __shfl_xor(y1, 32);                    \
    i32x4 w;                                                                   \
    w[0] = hi ? py0 : x0;  w[1] = hi ? py1 : x1;                               \
    w[2] = hi ? y0  : px0; w[3] = hi ? y1  : px1;                              \
    dst = __builtin_bit_cast(bf16x8, w);                                       \
  } while (0)

  int cur = 0;
  STAGE_KV(0, 0);
  __syncthreads();

  for (int t = 0; t < nt; ++t) {
    const int kv0 = t * 64;
    if (t + 1 < nt) STAGE_KV((t+1)*64, cur ^ 1);

    if (kv0 <= qw0 + 63) {        // wave-active (any of its 64 q rows unmasked)
      const char* Kb = (const char*)Kl[cur];
      const char* Vb = (const char*)Vl[cur];

      // ---- S^T = K * Q^T : per ck load kf pair once, feed BOTH q-frags ----
      f32x16 st[2][2];            // [frag][kv-half]
      st[0][0] = (f32x16){}; st[0][1] = (f32x16){};
      st[1][0] = (f32x16){}; st[1][1] = (f32x16){};
#pragma unroll
      for (int ck = 0; ck < 4; ++ck) {
        const int so = ((ck*2 + hi) ^ (ql & 7)) << 4;
        bf16x8 kf0 = *reinterpret_cast<const bf16x8*>(Kb + ql*128 + so);
        bf16x8 kf1 = *reinterpret_cast<const bf16x8*>(Kb + (32 + ql)*128 + so);
#pragma unroll
        for (int f = 0; f < 2; ++f) {
          st[f][0] = __builtin_amdgcn_mfma_f32_32x32x16_bf16(kf0, qf[f][ck], st[f][0], 0, 0, 0);
          st[f][1] = __builtin_amdgcn_mfma_f32_32x32x16_bf16(kf1, qf[f][ck], st[f][1], 0, 0, 0);
        }
      }

      // ---- per-frag: mask, online softmax, P->bf16 frags ----
      bf16x8 pa[2][4];
#pragma unroll
      for (int f = 0; f < 2; ++f) {
        const int qrow = qw0 + f*32 + ql;
        if (kv0 + 63 > qw0 + f*32) {   // diagonal region for this frag
#pragma unroll
          for (int r = 0; r < 16; ++r) {
            const int kvr = kv0 + (r & 3) + 8*(r >> 2) + 4*hi;
            st[f][0][r] = (kvr      <= qrow) ? st[f][0][r] : NEG;
            st[f][1][r] = (kvr + 32 <= qrow) ? st[f][1][r] : NEG;
          }
        }

        float pm = st[f][0][0];
#pragma unroll
        for (int r = 1; r < 16; ++r) pm = fmaxf(pm, st[f][0][r]);
#pragma unroll
        for (int r = 0; r < 16; ++r) pm = fmaxf(pm, st[f][1][r]);
        pm = fmaxf(pm, __shfl_xor(pm, 32));

        const float mnew = fmaxf(m_[f], pm);     // >= 0 always
        const float corr = exp2f(m_[f] - mnew);  // in (0,1]
        m_[f] = mnew;

        float ls = 0.f;
#pragma unroll
        for (int r = 0; r < 16; ++r) {
          float p = exp2f(st[f][0][r] - mnew);   // <= 1; masked -> exact 0
          ls += p;
          st[f][0][r] = p;
        }
#pragma unroll
        for (int r = 0; r < 16; ++r) {
          float p = exp2f(st[f][1][r] - mnew);
          ls += p;
          st[f][1][r] = p;
        }
        l_[f] = l_[f] * corr + (ls + __shfl_xor(ls, 32));
        o_[f][0] *= corr; o_[f][1] *= corr;

        MK_PA(pa[f][0], st[f][0], 0);
        MK_PA(pa[f][1], st[f][0], 8);
        MK_PA(pa[f][2], st[f][1], 0);
        MK_PA(pa[f][3], st[f][1], 8);
      }

      // ---- O^T += V^T * P^T : per ck load vf pair once, feed BOTH q-frags ----
#pragma unroll
      for (int ck = 0; ck < 4; ++ck) {
        const int so = ((ck*2 + hi) ^ (ql & 7)) << 4;
        bf16x8 vf0 = *reinterpret_cast<const bf16x8*>(Vb + ql*128 + so);
        bf16x8 vf1 = *reinterpret_cast<const bf16x8*>(Vb + (32 + ql)*128 + so);
#pragma unroll
        for (int f = 0; f < 2; ++f) {
          o_[f][0] = __builtin_amdgcn_mfma_f32_32x32x16_bf16(vf0, pa[f][ck], o_[f][0], 0, 0, 0);
          o_[f][1] = __builtin_amdgcn_mfma_f32_32x32x16_bf16(vf1, pa[f][ck], o_[f][1], 0, 0, 0);
        }
      }
    }

    __syncthreads();
    cur ^= 1;
  }

  // ---- epilogue: O /= l, store [B,S,H,DK] bf16 (q lane-local, dk in regs) ----
#pragma unroll
  for (int f = 0; f < 2; ++f) {
    const float linv = 1.0f / l_[f];
    const int qrow = qw0 + f*32 + ql;
    bf16* orow = O + ((size_t)(b*S_ + qrow)*H_ + hh)*DK_;
#pragma unroll
    for (int w4 = 0; w4 < 4; ++w4) {
      bf16x4 s0, s1;
#pragma unroll
      for (int e = 0; e < 4; ++e) {
        s0[e] = (bf16)(o_[f][0][w4*4 + e] * linv);
        s1[e] = (bf16)(o_[f][1][w4*4 + e] * linv);
      }
      *reinterpret_cast<bf16x4*>(orow + 8*w4 + 4*hi)      = s0;   // dk = 8*w4+4*hi+e
      *reinterpret_cast<bf16x4*>(orow + 32 + 8*w4 + 4*hi) = s1;   // +32
    }
  }
#undef STAGE_KV
#undef MK_PA
}

// ---------------- launch ----------------
extern "C" void kernel_launch(void* const* d_in, const int* in_sizes, int n_in,
                              void* d_out, int out_size, void* d_ws, size_t ws_size,
                              hipStream_t stream)
{
  const float* q    = (const float*)d_in[0];
  const float* k    = (const float*)d_in[1];
  const float* v    = (const float*)d_in[2];
  // d_in[3] = mask (causal tril; implemented analytically)
  const float* wq_w = (const float*)d_in[4];
  const float* wq_b = (const float*)d_in[5];
  const float* wk_w = (const float*)d_in[6];
  const float* wk_b = (const float*)d_in[7];
  const float* wv_w = (const float*)d_in[8];
  const float* wv_b = (const float*)d_in[9];
  const float* wo_w = (const float*)d_in[10];
  const float* wo_b = (const float*)d_in[11];

  const size_t XN = (size_t)M_ * D_;   // 4Mi elems
  const size_t WN = (size_t)D_ * D_;   // 1Mi elems
  bf16* ws  = (bf16*)d_ws;
  bf16* xq  = ws;                // 3*XN: xq,xk,xv bf16
  bf16* wqb = ws + 3*XN;         // 4*WN: wq,wk,wv,wo bf16
  bf16* Qs  = wqb + 4*WN;        // XN  [B,H,S,DK]  (pre-scaled)
  bf16* Ks  = Qs + XN;           // XN  [B,H,S,DK]
  bf16* Vts = Ks + XN;           // XN  [B,H,DK,S]
  bf16* Os  = ws;                // XN  [B,S,H,DK] — reuses xq (dead after proj GEMM)

  cast_kernel<<<dim3(8192), dim3(256), 0, stream>>>(q, k, v, wq_w, wk_w, wv_w, wo_w, xq);
  gemm_qkv_kernel<<<dim3(8, 32, 3), dim3(256), 0, stream>>>(
      xq, wqb, wq_b, wk_b, wv_b, Qs, Ks, Vts);
  attn_kernel<<<dim3(512), dim3(128), 0, stream>>>(Qs, Ks, Vts, Os);
  gemm_out_kernel<<<dim3(8, 64), dim3(256), 0, stream>>>(Os, wqb + 3*WN, wo_b, (float*)d_out);
}